// Round 1
// baseline (327.065 us; speedup 1.0000x reference)
//
#include <hip/hip_runtime.h>

// ISTFT->STFT->phase->ISTFT fused kernel. N_FFT=16, HOP=4, PAD=8.
// B=32, K=9 bins, T=65536 frames, Lw=(T-1)*4=262140 output samples/batch.
// One block = one batch row x 1024 output samples. Entire pipeline in LDS.

#define KB    9
#define TFR   65536
#define LW    262140
#define TILE  1024
#define NW    1048      // wav tile: [l0-12, l0+1036)
#define NCA   265       // mag columns: [l0/4-4, l0/4+261)
#define NFB   259       // spec frames: [l0/4-1, l0/4+258)

__device__ __constant__ float COS16[16] = {
   1.0f,  0.92387953f,  0.70710678f,  0.38268343f,  0.0f, -0.38268343f, -0.70710678f, -0.92387953f,
  -1.0f, -0.92387953f, -0.70710678f, -0.38268343f,  0.0f,  0.38268343f,  0.70710678f,  0.92387953f };
__device__ __constant__ float SIN16[16] = {
   0.0f,  0.38268343f,  0.70710678f,  0.92387953f,  1.0f,  0.92387953f,  0.70710678f,  0.38268343f,
   0.0f, -0.38268343f, -0.70710678f, -0.92387953f, -1.0f, -0.92387953f, -0.70710678f, -0.38268343f };

__global__ __launch_bounds__(256) void istft_fused(
    const float* __restrict__ mag, const float* __restrict__ win,
    float* __restrict__ out)
{
  __shared__ float s_w[16], s_c[16], s_s[16];
  __shared__ float s_mag[KB][NCA];       // 2385 floats
  __shared__ float s_wav[NW];            // 1048
  __shared__ float s_spec[NFB][2*KB];    // 4662 (re,im interleaved)
  __shared__ float s_fc[NFB][16];        // 4144 (w[n]*irfft, /16 deferred)

  const int tid  = threadIdx.x;
  const int l0   = blockIdx.x * TILE;
  const int b    = blockIdx.y;
  const int wbase = l0 - 12;
  const int tAlo  = (l0 >> 2) - 4;
  const int tBlo  = (l0 >> 2) - 1;

  if (tid < 16) {
    s_w[tid] = win[tid];
    s_c[tid] = COS16[tid];
    s_s[tid] = SIN16[tid];
  }

  // ---- load magnitude tile (coalesced per-bin rows) ----
  const float* magb = mag + (size_t)b * KB * TFR;
  for (int i = tid; i < KB * NCA; i += 256) {
    int k = i / NCA;
    int col = i - k * NCA;
    int t = tAlo + col;
    s_mag[k][col] = (t >= 0 && t < TFR) ? magb[k * TFR + t] : 0.f;
  }
  __syncthreads();

  // ---- stage A: first ISTFT (mag as real spectrum) -> wav tile ----
  for (int i = tid; i < NW; i += 256) {
    int m = wbase + i;                 // global wav index
    float outv = 0.f;
    if (m >= 0 && m < LW) {
      int q = m + 8;                   // index in un-sliced OLA array
      int tq = q >> 2, r = q & 3;
      float acc = 0.f, env = 0.f;
#pragma unroll
      for (int j = 0; j < 4; ++j) {
        int t = tq - j;
        if (t >= 0 && t < TFR) {
          int n = r + 4 * j;
          int col = t - tAlo;
          float v = s_mag[0][col] + ((n & 1) ? -s_mag[8][col] : s_mag[8][col]);
#pragma unroll
          for (int k = 1; k < 8; ++k)
            v += 2.f * s_mag[k][col] * s_c[(k * n) & 15];
          float wn = s_w[n];
          acc += wn * v;
          env += wn * wn;
        }
      }
      outv = acc / (16.f * env);       // fold irfft 1/16 into the divide
    }
    s_wav[i] = outv;
  }
  __syncthreads();

  // ---- stage B: STFT (reflect pad 8) + phase recombine -> spec tile ----
  for (int i = tid; i < NFB * KB; i += 256) {
    int f = i / KB;
    int k = i - f * KB;
    int t2 = tBlo + f;
    float pr = 0.f, pi = 0.f;
    if (t2 >= 0 && t2 < TFR) {
      float Sr = 0.f, Si = 0.f;
      int g0 = 4 * t2 - 8;             // wav-space index of tap n=0
#pragma unroll
      for (int n = 0; n < 16; ++n) {
        int g = g0 + n;
        if (g < 0) g = -g;                       // reflect left
        else if (g >= LW) g = 2 * (LW - 1) - g;  // reflect right
        float x = s_wav[g - wbase] * s_w[n];
        int j = (k * n) & 15;
        Sr += x * s_c[j];
        Si -= x * s_s[j];
      }
      float m = s_mag[k][t2 - tAlo];
      float rr = sqrtf(Sr * Sr + Si * Si);
      if (rr > 0.f) { pr = m * Sr / rr; pi = m * Si / rr; }
      else          { pr = m; pi = 0.f; }        // atan2(0,0)=0 -> (mag, 0)
    }
    s_spec[f][2 * k]     = pr;
    s_spec[f][2 * k + 1] = pi;
  }
  __syncthreads();

  // ---- stage C1: irfft of spec frames, pre-window ----
  for (int i = tid; i < NFB * 16; i += 256) {
    int f = i >> 4;
    int n = i & 15;
    float R0 = s_spec[f][0];
    float R8 = s_spec[f][16];
    float v = R0 + ((n & 1) ? -R8 : R8);
#pragma unroll
    for (int k = 1; k < 8; ++k) {
      int j = (k * n) & 15;
      v += 2.f * (s_spec[f][2 * k] * s_c[j] - s_spec[f][2 * k + 1] * s_s[j]);
    }
    s_fc[f][n] = s_w[n] * v;           // /16 deferred to final divide
  }
  __syncthreads();

  // ---- stage C2: final OLA + env divide -> output ----
  float* outb = out + (size_t)b * LW;
  for (int i = tid; i < TILE; i += 256) {
    int l = l0 + i;
    if (l < LW) {
      int q = l + 8;
      int tq = q >> 2, r = q & 3;
      float acc = 0.f, env = 0.f;
#pragma unroll
      for (int j = 0; j < 4; ++j) {
        int t = tq - j;
        if (t >= 0 && t < TFR) {
          int n = r + 4 * j;
          acc += s_fc[t - tBlo][n];
          float wn = s_w[n];
          env += wn * wn;
        }
      }
      outb[l] = acc / (16.f * env);
    }
  }
}

extern "C" void kernel_launch(void* const* d_in, const int* in_sizes, int n_in,
                              void* d_out, int out_size, void* d_ws, size_t ws_size,
                              hipStream_t stream) {
  const float* mag = (const float*)d_in[0];   // (32, 9, 65536) f32
  const float* win = (const float*)d_in[1];   // (16,) f32
  float* out = (float*)d_out;                 // (32, 262140) f32
  dim3 grid((LW + TILE - 1) / TILE, 32);      // 256 x 32 blocks
  istft_fused<<<grid, 256, 0, stream>>>(mag, win, out);
}

// Round 2
// 192.300 us; speedup vs baseline: 1.7008x; 1.7008x over previous
//
#include <hip/hip_runtime.h>

// Fully fused mag -> ISTFT -> STFT -> phase -> ISTFT. N_FFT=16, HOP=4, PAD=8.
// B=32, K=9 bins, T=65536 frames, LW=262140 samples/batch.
// One block = one batch row x 1024 output samples; one thread = one frame in
// the DFT stages, with fully unrolled constant-twiddle 16-pt transforms.

#define KB    9
#define TFR   65536
#define LW    262140
#define TILE  1024
#define NW    1048      // wav tile [l0-12, l0+1036)
#define NCA   265       // stage-A frames [l0/4-4, l0/4+261)
#define NFB   259       // stage-B frames [l0/4-1, l0/4+258)
#define MSTR  268       // s_mag row stride (mult of 4 for b128)
#define FSTR  20        // frame-row stride (mult of 4, non-pow2 banks)

#define C1f 0.9238795325112867f
#define C2f 0.7071067811865476f
#define C3f 0.3826834323650898f

#define W1 0.03806023374435663f
#define W2 0.14644660940672627f
#define W3 0.30865828381745514f
#define W4 0.5f
#define W5 0.6913417161825449f
#define W6 0.8535533905932737f
#define W7 0.9619397662556434f

__device__ __constant__ float W2C[16] = {
  0.f, W1*W1, W2*W2, W3*W3, 0.25f, W5*W5, W6*W6, W7*W7,
  1.f, W7*W7, W6*W6, W5*W5, 0.25f, W3*W3, W2*W2, W1*W1 };

__global__ __launch_bounds__(256) void istft_fused(
    const float* __restrict__ mag, float* __restrict__ out)
{
  __shared__ __align__(16) float s_mag[KB * MSTR];   // 9648 B
  __shared__ __align__(16) float s_fab[NCA * FSTR];  // 21200 B (fa then fc)
  __shared__ __align__(16) float s_wav[NW];          // 4192 B

  const int tid = threadIdx.x;
  const int bx  = blockIdx.x;
  const int b   = blockIdx.y;
  const int l0  = bx << 10;
  const int t4  = l0 >> 2;
  const int tAlo = t4 - 4;
  const int tBlo = t4 - 1;
  const int wbase = l0 - 12;
  const bool edge = (bx == 0) || (bx == (int)gridDim.x - 1);

  // ---- load magnitude tile ----
  const float* magb = mag + (size_t)b * (size_t)(KB * TFR);
#pragma unroll
  for (int k = 0; k < KB; ++k) {
    const float* mrow = magb + (size_t)k * TFR + tAlo;
    for (int c = tid; c < NCA; c += 256) {
      int t = tAlo + c;
      s_mag[k * MSTR + c] = ((unsigned)t < (unsigned)TFR) ? mrow[c] : 0.f;
    }
  }
  __syncthreads();

  // ---- A1: per-frame irfft16 of mag (real spectrum -> symmetric frame), windowed ----
  for (int f = tid; f < NCA; f += 256) {
    float R0 = s_mag[0*MSTR+f], R1 = s_mag[1*MSTR+f], R2 = s_mag[2*MSTR+f],
          R3 = s_mag[3*MSTR+f], R4 = s_mag[4*MSTR+f], R5 = s_mag[5*MSTR+f],
          R6 = s_mag[6*MSTR+f], R7 = s_mag[7*MSTR+f], R8 = s_mag[8*MSTR+f];
    float p1=R1+R7, m1=R1-R7, p2=R2+R6, m2=R2-R6, p3=R3+R5, m3=R3-R5;
    float tp=R0+R8, tm=R0-R8, d13=p1-p3;
    float E0 = fmaf(2.f, ((p1+p2)+(p3+R4)), tp);
    float E1 = fmaf(2.f, fmaf(C1f,m1, fmaf(C2f,m2, C3f*m3)), tm);
    float E2 = fmaf(2.f, fmaf(C2f,d13, -R4), tp);
    float E3 = fmaf(2.f, fmaf(C3f,m1, fmaf(-C2f,m2, -C1f*m3)), tm);
    float E4 = fmaf(2.f, R4-p2, tp);
    float E5 = fmaf(2.f, fmaf(-C3f,m1, fmaf(-C2f,m2, C1f*m3)), tm);
    float E6 = fmaf(-2.f, fmaf(C2f,d13, R4), tp);
    float E7 = fmaf(2.f, fmaf(-C1f,m1, fmaf(C2f,m2, -C3f*m3)), tm);
    float E8 = fmaf(2.f, ((p2+R4)-(p1+p3)), tp);
    float* rp = s_fab + f * FSTR;
    *(float4*)(rp+0)  = make_float4(0.f,   W1*E1, W2*E2, W3*E3);
    *(float4*)(rp+4)  = make_float4(W4*E4, W5*E5, W6*E6, W7*E7);
    *(float4*)(rp+8)  = make_float4(E8,    W7*E7, W6*E6, W5*E5);
    *(float4*)(rp+12) = make_float4(W4*E4, W3*E3, W2*E2, W1*E1);
  }
  __syncthreads();

  // ---- A2: OLA + env divide -> wav tile ----
  if (!edge) {
    for (int t = tid; t < NW/4; t += 256) {   // one float4 of wav per thread
      const float* r3p = s_fab + t * FSTR;
      float4 a  = *(const float4*)(r3p + 3*FSTR);
      float4 bb = *(const float4*)(r3p + 2*FSTR + 4);
      float4 cc = *(const float4*)(r3p + 1*FSTR + 8);
      float4 dd = *(const float4*)(r3p + 12);
      float4 o;
      o.x = (a.x+bb.x+cc.x+dd.x) * (1.f/24.f);
      o.y = (a.y+bb.y+cc.y+dd.y) * (1.f/24.f);
      o.z = (a.z+bb.z+cc.z+dd.z) * (1.f/24.f);
      o.w = (a.w+bb.w+cc.w+dd.w) * (1.f/24.f);
      *(float4*)(s_wav + 4*t) = o;
    }
  } else {
    for (int i = tid; i < NW; i += 256) {
      int m = wbase + i;
      float val = 0.f;
      if (m >= 0 && m < LW) {
        int q = m + 8;
        int tq = q >> 2, r = q & 3;
        int base = (tq - tAlo) * FSTR + r;
        float acc = 0.f, env = 0.f;
#pragma unroll
        for (int j = 0; j < 4; ++j) {
          int t = tq - j;
          if ((unsigned)t < (unsigned)TFR) { acc += s_fab[base - 16*j]; env += W2C[r + 4*j]; }
        }
        val = acc * __builtin_amdgcn_rcpf(16.f * env);
      }
      s_wav[i] = val;
    }
  }
  __syncthreads();

  // ---- B + C1: per-frame STFT -> phase recombine -> irfft16, windowed ----
  for (int f = tid; f < NFB; f += 256) {
    float* rp = s_fab + f * FSTR;     // overwrite as fc rows (fa fully consumed)
    float x1=0,x2=0,x3=0,x4=0,x5=0,x6=0,x7=0,x8w=0,
          x9=0,x10=0,x11=0,x12=0,x13=0,x14=0,x15=0;
    bool valid = true;
    if (!edge) {
      const float4* wp = (const float4*)(s_wav + 4*f);
      float4 a0 = wp[0], a1 = wp[1], a2 = wp[2], a3 = wp[3];
      x1=a0.y; x2=a0.z; x3=a0.w; x4=a1.x; x5=a1.y; x6=a1.z; x7=a1.w;
      x8w=a2.x; x9=a2.y; x10=a2.z; x11=a2.w; x12=a3.x; x13=a3.y; x14=a3.z; x15=a3.w;
    } else {
      int t2 = tBlo + f;
      valid = ((unsigned)t2 < (unsigned)TFR);
      if (valid) {
        float xs[16];
        int g0 = 4*t2 - 8;
#pragma unroll
        for (int n = 0; n < 16; ++n) {
          int g = g0 + n;
          g = (g < 0) ? -g : g;                       // reflect left
          g = (g < LW) ? g : (2*(LW-1) - g);          // reflect right
          xs[n] = s_wav[g - wbase];
        }
        x1=xs[1]; x2=xs[2]; x3=xs[3]; x4=xs[4]; x5=xs[5]; x6=xs[6]; x7=xs[7];
        x8w=xs[8]; x9=xs[9]; x10=xs[10]; x11=xs[11]; x12=xs[12]; x13=xs[13];
        x14=xs[14]; x15=xs[15];
      }
    }
    if (valid) {
      // window (w0=0 kills tap 0; w8=1)
      x1*=W1; x2*=W2; x3*=W3; x4*=W4; x5*=W5; x6*=W6; x7*=W7;
      x9*=W7; x10*=W6; x11*=W5; x12*=W4; x13*=W3; x14*=W2; x15*=W1;
      float u1=x1+x15, v1=x1-x15, u2=x2+x14, v2=x2-x14, u3=x3+x13, v3=x3-x13,
            u4=x4+x12, v4=x4-x12, u5=x5+x11, v5=x5-x11, u6=x6+x10, v6=x6-x10,
            u7=x7+x9,  v7=x7-x9;
      float P1=u1+u7, M1=u1-u7, P2=u2+u6, M2=u2-u6, P3=u3+u5, M3=u3-u5;
      float D13 = P1-P3;
      float Sr0 = x8w + ((P1+P2)+(P3+u4));
      float Sr1 = fmaf(C1f,M1, fmaf(C2f,M2, C3f*M3)) - x8w;
      float Sr2 = fmaf(C2f,D13, x8w - u4);
      float Sr3 = fmaf(C3f,M1, fmaf(-C2f,M2, -C1f*M3)) - x8w;
      float Sr4 = (u4 - P2) + x8w;
      float Sr5 = fmaf(-C3f,M1, fmaf(-C2f,M2, C1f*M3)) - x8w;
      float Sr6 = fmaf(-C2f,D13, x8w - u4);
      float Sr7 = fmaf(-C1f,M1, fmaf(C2f,M2, -C3f*M3)) - x8w;
      float Sr8 = x8w + ((P2+u4)-(P1+P3));
      float Q1=v1+v7, N1=v1-v7, Q2=v2+v6, N2=v2-v6, Q3=v3+v5, N3=v3-v5;
      float NN = N1+N3;
      float Si1 = -(fmaf(C3f,Q1, fmaf(C2f,Q2, C1f*Q3)) + v4);
      float Si2 = -fmaf(C2f,NN, N2);
      float Si3 = -(fmaf(C1f,Q1, fmaf(C2f,Q2, -C3f*Q3)) - v4);
      float Si4 = N3 - N1;
      float Si5 = -(fmaf(C1f,Q1, fmaf(-C2f,Q2, -C3f*Q3)) + v4);
      float Si6 = fmaf(-C2f,NN, N2);
      float Si7 = -(fmaf(C3f,Q1, fmaf(-C2f,Q2, C1f*Q3)) - v4);

      const float* mcol = s_mag + (f + 3);   // tBlo - tAlo == 3
      float pr0,pr1,pr2,pr3,pr4,pr5,pr6,pr7,pr8;
      float pi1,pi2,pi3,pi4,pi5,pi6,pi7;
#define PHASE(PRk, PIk, kk, SR, SI) { \
        float mm = mcol[kk*MSTR]; \
        float r2 = fmaf(SR,SR, (SI)*(SI)); \
        float rin = (r2 > 0.f) ? __builtin_amdgcn_rsqf(r2) : 0.f; \
        float mr = mm * rin; \
        PRk = (r2 > 0.f) ? mr * (SR) : mm; \
        PIk = mr * (SI); }
      { float mm = mcol[0];
        pr0 = (Sr0 != 0.f) ? ((Sr0 > 0.f) ? mm : -mm) : mm; }
      PHASE(pr1, pi1, 1, Sr1, Si1)
      PHASE(pr2, pi2, 2, Sr2, Si2)
      PHASE(pr3, pi3, 3, Sr3, Si3)
      PHASE(pr4, pi4, 4, Sr4, Si4)
      PHASE(pr5, pi5, 5, Sr5, Si5)
      PHASE(pr6, pi6, 6, Sr6, Si6)
      PHASE(pr7, pi7, 7, Sr7, Si7)
      { float mm = mcol[8*MSTR];
        pr8 = (Sr8 != 0.f) ? ((Sr8 > 0.f) ? mm : -mm) : mm; }
#undef PHASE

      // irfft16 of (pr + i*pi): even part from pr, odd from pi
      float ap1=pr1+pr7, bm1=pr1-pr7, ap2=pr2+pr6, bm2=pr2-pr6, ap3=pr3+pr5, bm3=pr3-pr5;
      float tp=pr0+pr8, tm=pr0-pr8, e13=ap1-ap3;
      float E0 = fmaf(2.f, ((ap1+ap2)+(ap3+pr4)), tp);
      float E1 = fmaf(2.f, fmaf(C1f,bm1, fmaf(C2f,bm2, C3f*bm3)), tm);
      float E2 = fmaf(2.f, fmaf(C2f,e13, -pr4), tp);
      float E3 = fmaf(2.f, fmaf(C3f,bm1, fmaf(-C2f,bm2, -C1f*bm3)), tm);
      float E4 = fmaf(2.f, pr4-ap2, tp);
      float E5 = fmaf(2.f, fmaf(-C3f,bm1, fmaf(-C2f,bm2, C1f*bm3)), tm);
      float E6 = fmaf(-2.f, fmaf(C2f,e13, pr4), tp);
      float E7 = fmaf(2.f, fmaf(-C1f,bm1, fmaf(C2f,bm2, -C3f*bm3)), tm);
      float E8 = fmaf(2.f, ((ap2+pr4)-(ap1+ap3)), tp);
      float q1=pi1+pi7, n1=pi1-pi7, q2=pi2+pi6, n2=pi2-pi6, q3=pi3+pi5, n3=pi3-pi5;
      float nn = n1+n3;
      float O1 = -2.f*(fmaf(C3f,q1, fmaf(C2f,q2, C1f*q3)) + pi4);
      float O2 = -2.f*fmaf(C2f,nn, n2);
      float O3 = -2.f*(fmaf(C1f,q1, fmaf(C2f,q2, -C3f*q3)) - pi4);
      float O4 = -2.f*(n1-n3);
      float O5 = -2.f*(fmaf(C1f,q1, fmaf(-C2f,q2, -C3f*q3)) + pi4);
      float O6 = -2.f*fmaf(C2f,nn, -n2);
      float O7 = -2.f*(fmaf(C3f,q1, fmaf(-C2f,q2, C1f*q3)) - pi4);

      *(float4*)(rp+0)  = make_float4(0.f,          W1*(E1+O1), W2*(E2+O2), W3*(E3+O3));
      *(float4*)(rp+4)  = make_float4(W4*(E4+O4),   W5*(E5+O5), W6*(E6+O6), W7*(E7+O7));
      *(float4*)(rp+8)  = make_float4(E8,           W7*(E7-O7), W6*(E6-O6), W5*(E5-O5));
      *(float4*)(rp+12) = make_float4(W4*(E4-O4),   W3*(E3-O3), W2*(E2-O2), W1*(E1-O1));
    } else {
      float4 z = make_float4(0.f,0.f,0.f,0.f);
      *(float4*)(rp+0)=z; *(float4*)(rp+4)=z; *(float4*)(rp+8)=z; *(float4*)(rp+12)=z;
    }
  }
  __syncthreads();

  // ---- C2: final OLA + env divide -> output ----
  float* outb = out + (size_t)b * LW;
  if (!edge) {
    const float* r3p = s_fab + tid * FSTR;
    float4 a  = *(const float4*)(r3p + 3*FSTR);
    float4 bb = *(const float4*)(r3p + 2*FSTR + 4);
    float4 cc = *(const float4*)(r3p + 1*FSTR + 8);
    float4 dd = *(const float4*)(r3p + 12);
    float4 o;
    o.x = (a.x+bb.x+cc.x+dd.x) * (1.f/24.f);
    o.y = (a.y+bb.y+cc.y+dd.y) * (1.f/24.f);
    o.z = (a.z+bb.z+cc.z+dd.z) * (1.f/24.f);
    o.w = (a.w+bb.w+cc.w+dd.w) * (1.f/24.f);
    *(float4*)(outb + l0 + 4*tid) = o;
  } else {
    for (int i = tid; i < TILE; i += 256) {
      int l = l0 + i;
      if (l < LW) {
        int q = l + 8;
        int tq = q >> 2, r = q & 3;
        int base = (tq - tBlo) * FSTR + r;
        float acc = 0.f, env = 0.f;
#pragma unroll
        for (int j = 0; j < 4; ++j) {
          int t = tq - j;
          if ((unsigned)t < (unsigned)TFR) { acc += s_fab[base - 16*j]; env += W2C[r + 4*j]; }
        }
        outb[l] = acc * __builtin_amdgcn_rcpf(16.f * env);
      }
    }
  }
}

extern "C" void kernel_launch(void* const* d_in, const int* in_sizes, int n_in,
                              void* d_out, int out_size, void* d_ws, size_t ws_size,
                              hipStream_t stream) {
  const float* mag = (const float*)d_in[0];   // (32, 9, 65536) f32
  float* out = (float*)d_out;                 // (32, 262140) f32
  dim3 grid((LW + TILE - 1) / TILE, 32);      // 256 x 32
  istft_fused<<<grid, 256, 0, stream>>>(mag, out);
}

// Round 3
// 130.061 us; speedup vs baseline: 2.5147x; 1.4785x over previous
//
#include <hip/hip_runtime.h>

// Fully fused mag -> ISTFT -> STFT -> phase -> ISTFT, wave-parallel version.
// N_FFT=16, HOP=4, PAD=8. B=32, K=9 bins, T=65536 frames, LW=262140.
// Main kernel: lane = frame. All inter-frame data exchange via __shfl
// (ds_bpermute) -- zero LDS, zero barriers. Each wave produces 55 output
// frames (lanes 4..58); 4-lane halo on each side. Interior only
// (t in [256, 65280)): no reflect-pad, env == 1.5 everywhere.
// Edge kernel: R2's validated LDS path for the first/last 1024 samples.

#define KB    9
#define TFR   65536
#define LW    262140

#define C1f 0.9238795325112867f
#define C2f 0.7071067811865476f
#define C3f 0.3826834323650898f

#define W1 0.03806023374435663f
#define W2 0.14644660940672627f
#define W3 0.30865828381745514f
#define W4 0.5f
#define W5 0.6913417161825449f
#define W6 0.8535533905932737f
#define W7 0.9619397662556434f

// ---------------- main interior kernel: 1 lane = 1 frame ----------------

#define FRAMES_PER_WAVE 55
#define TMIN 256
#define TMAX 65280    // main kernel covers out frames [256, 65280)

__global__ __launch_bounds__(256) void istft_wave(
    const float* __restrict__ mag, float* __restrict__ out)
{
  const int tid  = threadIdx.x;
  const int lane = tid & 63;
  const int b    = blockIdx.y;
  const int wv   = blockIdx.x * 4 + (tid >> 6);       // wave index in batch
  const int t    = TMIN + wv * FRAMES_PER_WAVE - 4 + lane;  // this lane's frame

  // ---- load mag column t (9 bins, coalesced across lanes) ----
  const float* magb = mag + (size_t)b * (size_t)(KB * TFR);
  float R0 = magb[0*TFR + t], R1 = magb[1*TFR + t], R2 = magb[2*TFR + t],
        R3 = magb[3*TFR + t], R4 = magb[4*TFR + t], R5 = magb[5*TFR + t],
        R6 = magb[6*TFR + t], R7 = magb[7*TFR + t], R8 = magb[8*TFR + t];

  // ---- stage A: irfft16 of real spectrum (even-symmetric frame), windowed.
  // fa[n] = w[n]*x[n]; x symmetric => distinct values f1..f8 (fa[0]=0).
  float f1,f2,f3,f4,f5,f6,f7,f8;
  {
    float p1=R1+R7, m1=R1-R7, p2=R2+R6, m2=R2-R6, p3=R3+R5, m3=R3-R5;
    float tp=R0+R8, tm=R0-R8, d13=p1-p3;
    float E1 = fmaf(2.f, fmaf(C1f,m1, fmaf(C2f,m2, C3f*m3)), tm);
    float E2 = fmaf(2.f, fmaf(C2f,d13, -R4), tp);
    float E3 = fmaf(2.f, fmaf(C3f,m1, fmaf(-C2f,m2, -C1f*m3)), tm);
    float E4 = fmaf(2.f, R4-p2, tp);
    float E5 = fmaf(2.f, fmaf(-C3f,m1, fmaf(-C2f,m2, C1f*m3)), tm);
    float E6 = fmaf(-2.f, fmaf(C2f,d13, R4), tp);
    float E7 = fmaf(2.f, fmaf(-C1f,m1, fmaf(C2f,m2, -C3f*m3)), tm);
    float E8 = fmaf(2.f, ((p2+R4)-(p1+p3)), tp);
    f1=W1*E1; f2=W2*E2; f3=W3*E3; f4=W4*E4; f5=W5*E5; f6=W6*E6; f7=W7*E7; f8=E8;
  }

  // ---- stage A2: OLA -> this lane's wav chunk wav[4t..4t+3] (11 shuffles).
  // wav[4t+r] = (fa_{t+2}[r] + fa_{t+1}[r+4] + fa_t[r+8] + fa_{t-1}[r+12])/24
  float wc0, wc1, wc2, wc3;
  {
    float f4p1 = __shfl(f4, lane+1, 64);
    float f5p1 = __shfl(f5, lane+1, 64);
    float f6p1 = __shfl(f6, lane+1, 64);
    float f7p1 = __shfl(f7, lane+1, 64);
    float f1m1 = __shfl(f1, lane-1, 64);
    float f2m1 = __shfl(f2, lane-1, 64);
    float f3m1 = __shfl(f3, lane-1, 64);
    float f4m1 = __shfl(f4, lane-1, 64);
    float f1p2 = __shfl(f1, lane+2, 64);
    float f2p2 = __shfl(f2, lane+2, 64);
    float f3p2 = __shfl(f3, lane+2, 64);
    wc0 = (f4p1 + f8 + f4m1) * (1.f/24.f);
    wc1 = (f1p2 + f5p1 + f7 + f3m1) * (1.f/24.f);
    wc2 = (f2p2 + f6p1 + f6 + f2m1) * (1.f/24.f);
    wc3 = (f3p2 + f7p1 + f5 + f1m1) * (1.f/24.f);
  }

  // ---- stage B: gather xs[1..15] = wav[4t-8+n] (11 shuffles; xs[0] unused)
  float x1  = __shfl(wc1, lane-2, 64);
  float x2  = __shfl(wc2, lane-2, 64);
  float x3  = __shfl(wc3, lane-2, 64);
  float x4  = __shfl(wc0, lane-1, 64);
  float x5  = __shfl(wc1, lane-1, 64);
  float x6  = __shfl(wc2, lane-1, 64);
  float x7  = __shfl(wc3, lane-1, 64);
  float x8w = wc0, x9 = wc1, x10 = wc2, x11 = wc3;
  float x12 = __shfl(wc0, lane+1, 64);
  float x13 = __shfl(wc1, lane+1, 64);
  float x14 = __shfl(wc2, lane+1, 64);
  float x15 = __shfl(wc3, lane+1, 64);

  // window (w0=0 kills tap 0; w8=1)
  x1*=W1; x2*=W2; x3*=W3; x4*=W4; x5*=W5; x6*=W6; x7*=W7;
  x9*=W7; x10*=W6; x11*=W5; x12*=W4; x13*=W3; x14*=W2; x15*=W1;

  float fc1,fc2,fc3,fc4,fc5,fc6,fc7,fc8,fc9,fc10,fc11,fc12,fc13,fc14,fc15;
  {
    float u1=x1+x15, v1=x1-x15, u2=x2+x14, v2=x2-x14, u3=x3+x13, v3=x3-x13,
          u4=x4+x12, v4=x4-x12, u5=x5+x11, v5=x5-x11, u6=x6+x10, v6=x6-x10,
          u7=x7+x9,  v7=x7-x9;
    float P1=u1+u7, M1=u1-u7, P2=u2+u6, M2=u2-u6, P3=u3+u5, M3=u3-u5;
    float D13 = P1-P3;
    float Sr0 = x8w + ((P1+P2)+(P3+u4));
    float Sr1 = fmaf(C1f,M1, fmaf(C2f,M2, C3f*M3)) - x8w;
    float Sr2 = fmaf(C2f,D13, x8w - u4);
    float Sr3 = fmaf(C3f,M1, fmaf(-C2f,M2, -C1f*M3)) - x8w;
    float Sr4 = (u4 - P2) + x8w;
    float Sr5 = fmaf(-C3f,M1, fmaf(-C2f,M2, C1f*M3)) - x8w;
    float Sr6 = fmaf(-C2f,D13, x8w - u4);
    float Sr7 = fmaf(-C1f,M1, fmaf(C2f,M2, -C3f*M3)) - x8w;
    float Sr8 = x8w + ((P2+u4)-(P1+P3));
    float Q1=v1+v7, N1=v1-v7, Q2=v2+v6, N2=v2-v6, Q3=v3+v5, N3=v3-v5;
    float NN = N1+N3;
    float Si1 = -(fmaf(C3f,Q1, fmaf(C2f,Q2, C1f*Q3)) + v4);
    float Si2 = -fmaf(C2f,NN, N2);
    float Si3 = -(fmaf(C1f,Q1, fmaf(C2f,Q2, -C3f*Q3)) - v4);
    float Si4 = N3 - N1;
    float Si5 = -(fmaf(C1f,Q1, fmaf(-C2f,Q2, -C3f*Q3)) + v4);
    float Si6 = fmaf(-C2f,NN, N2);
    float Si7 = -(fmaf(C3f,Q1, fmaf(-C2f,Q2, C1f*Q3)) - v4);

    // phase recombine: spec_k = mag_k * S_k/|S_k|  (mag col t = R0..R8)
    float pr0,pr1,pr2,pr3,pr4,pr5,pr6,pr7,pr8;
    float pi1,pi2,pi3,pi4,pi5,pi6,pi7;
#define PHASE(PRk, PIk, MM, SR, SI) { \
      float r2 = fmaf(SR,SR, (SI)*(SI)); \
      float rin = (r2 > 0.f) ? __builtin_amdgcn_rsqf(r2) : 0.f; \
      float mr = (MM) * rin; \
      PRk = (r2 > 0.f) ? mr * (SR) : (MM); \
      PIk = mr * (SI); }
    pr0 = (Sr0 != 0.f) ? ((Sr0 > 0.f) ? R0 : -R0) : R0;
    PHASE(pr1, pi1, R1, Sr1, Si1)
    PHASE(pr2, pi2, R2, Sr2, Si2)
    PHASE(pr3, pi3, R3, Sr3, Si3)
    PHASE(pr4, pi4, R4, Sr4, Si4)
    PHASE(pr5, pi5, R5, Sr5, Si5)
    PHASE(pr6, pi6, R6, Sr6, Si6)
    PHASE(pr7, pi7, R7, Sr7, Si7)
    pr8 = (Sr8 != 0.f) ? ((Sr8 > 0.f) ? R8 : -R8) : R8;
#undef PHASE

    // irfft16 of (pr + i*pi), windowed -> fc[1..15] (fc[0]=0)
    float ap1=pr1+pr7, bm1=pr1-pr7, ap2=pr2+pr6, bm2=pr2-pr6, ap3=pr3+pr5, bm3=pr3-pr5;
    float tp=pr0+pr8, tm=pr0-pr8, ed=ap1-ap3;
    float E1 = fmaf(2.f, fmaf(C1f,bm1, fmaf(C2f,bm2, C3f*bm3)), tm);
    float E2 = fmaf(2.f, fmaf(C2f,ed, -pr4), tp);
    float E3 = fmaf(2.f, fmaf(C3f,bm1, fmaf(-C2f,bm2, -C1f*bm3)), tm);
    float E4 = fmaf(2.f, pr4-ap2, tp);
    float E5 = fmaf(2.f, fmaf(-C3f,bm1, fmaf(-C2f,bm2, C1f*bm3)), tm);
    float E6 = fmaf(-2.f, fmaf(C2f,ed, pr4), tp);
    float E7 = fmaf(2.f, fmaf(-C1f,bm1, fmaf(C2f,bm2, -C3f*bm3)), tm);
    float E8 = fmaf(2.f, ((ap2+pr4)-(ap1+ap3)), tp);
    float q1=pi1+pi7, n1=pi1-pi7, q2=pi2+pi6, n2=pi2-pi6, q3=pi3+pi5, n3=pi3-pi5;
    float nn = n1+n3;
    float O1 = -2.f*(fmaf(C3f,q1, fmaf(C2f,q2, C1f*q3)) + pi4);
    float O2 = -2.f*fmaf(C2f,nn, n2);
    float O3 = -2.f*(fmaf(C1f,q1, fmaf(C2f,q2, -C3f*q3)) - pi4);
    float O4 = -2.f*(n1-n3);
    float O5 = -2.f*(fmaf(C1f,q1, fmaf(-C2f,q2, -C3f*q3)) + pi4);
    float O6 = -2.f*fmaf(C2f,nn, -n2);
    float O7 = -2.f*(fmaf(C3f,q1, fmaf(-C2f,q2, C1f*q3)) - pi4);

    fc1 = W1*(E1+O1); fc2 = W2*(E2+O2); fc3 = W3*(E3+O3); fc4 = W4*(E4+O4);
    fc5 = W5*(E5+O5); fc6 = W6*(E6+O6); fc7 = W7*(E7+O7); fc8 = E8;
    fc9  = W7*(E7-O7); fc10 = W6*(E6-O6); fc11 = W5*(E5-O5); fc12 = W4*(E4-O4);
    fc13 = W3*(E3-O3); fc14 = W2*(E2-O2); fc15 = W1*(E1-O1);
  }

  // ---- stage C: final OLA (11 shuffles) -> out[4t..4t+3]
  float g1  = __shfl(fc1,  lane+2, 64);
  float g2  = __shfl(fc2,  lane+2, 64);
  float g3  = __shfl(fc3,  lane+2, 64);
  float h4  = __shfl(fc4,  lane+1, 64);
  float h5  = __shfl(fc5,  lane+1, 64);
  float h6  = __shfl(fc6,  lane+1, 64);
  float h7  = __shfl(fc7,  lane+1, 64);
  float q12 = __shfl(fc12, lane-1, 64);
  float q13 = __shfl(fc13, lane-1, 64);
  float q14 = __shfl(fc14, lane-1, 64);
  float q15 = __shfl(fc15, lane-1, 64);

  if (lane >= 4 && lane <= 58 && t < TMAX) {
    float4 o;
    o.x = (h4 + fc8  + q12) * (1.f/24.f);
    o.y = (g1 + h5 + fc9  + q13) * (1.f/24.f);
    o.z = (g2 + h6 + fc10 + q14) * (1.f/24.f);
    o.w = (g3 + h7 + fc11 + q15) * (1.f/24.f);
    *(float4*)(out + (size_t)b * LW + 4*(size_t)t) = o;
  }
}

// ---------------- edge kernel: validated R2 LDS path, edge blocks only ----

#define TILE  1024
#define NW    1048
#define NCA   265
#define NFB   259
#define MSTR  268
#define FSTR  20

__device__ __constant__ float W2C[16] = {
  0.f, W1*W1, W2*W2, W3*W3, 0.25f, W5*W5, W6*W6, W7*W7,
  1.f, W7*W7, W6*W6, W5*W5, 0.25f, W3*W3, W2*W2, W1*W1 };

__global__ __launch_bounds__(256) void istft_edge(
    const float* __restrict__ mag, float* __restrict__ out)
{
  __shared__ __align__(16) float s_mag[KB * MSTR];
  __shared__ __align__(16) float s_fab[NCA * FSTR];
  __shared__ __align__(16) float s_wav[NW];

  const int tid = threadIdx.x;
  const int b   = blockIdx.y;
  const int l0  = (blockIdx.x == 0) ? 0 : (LW / TILE) * TILE - TILE + 1024; // 0 or 261120
  const int t4  = l0 >> 2;
  const int tAlo = t4 - 4;
  const int tBlo = t4 - 1;
  const int wbase = l0 - 12;

  const float* magb = mag + (size_t)b * (size_t)(KB * TFR);
#pragma unroll
  for (int k = 0; k < KB; ++k) {
    const float* mrow = magb + (size_t)k * TFR + tAlo;
    for (int c = tid; c < NCA; c += 256) {
      int t = tAlo + c;
      s_mag[k * MSTR + c] = ((unsigned)t < (unsigned)TFR) ? mrow[c] : 0.f;
    }
  }
  __syncthreads();

  for (int f = tid; f < NCA; f += 256) {
    float R0 = s_mag[0*MSTR+f], R1 = s_mag[1*MSTR+f], R2 = s_mag[2*MSTR+f],
          R3 = s_mag[3*MSTR+f], R4 = s_mag[4*MSTR+f], R5 = s_mag[5*MSTR+f],
          R6 = s_mag[6*MSTR+f], R7 = s_mag[7*MSTR+f], R8 = s_mag[8*MSTR+f];
    float p1=R1+R7, m1=R1-R7, p2=R2+R6, m2=R2-R6, p3=R3+R5, m3=R3-R5;
    float tp=R0+R8, tm=R0-R8, d13=p1-p3;
    float E1 = fmaf(2.f, fmaf(C1f,m1, fmaf(C2f,m2, C3f*m3)), tm);
    float E2 = fmaf(2.f, fmaf(C2f,d13, -R4), tp);
    float E3 = fmaf(2.f, fmaf(C3f,m1, fmaf(-C2f,m2, -C1f*m3)), tm);
    float E4 = fmaf(2.f, R4-p2, tp);
    float E5 = fmaf(2.f, fmaf(-C3f,m1, fmaf(-C2f,m2, C1f*m3)), tm);
    float E6 = fmaf(-2.f, fmaf(C2f,d13, R4), tp);
    float E7 = fmaf(2.f, fmaf(-C1f,m1, fmaf(C2f,m2, -C3f*m3)), tm);
    float E8 = fmaf(2.f, ((p2+R4)-(p1+p3)), tp);
    float* rp = s_fab + f * FSTR;
    *(float4*)(rp+0)  = make_float4(0.f,   W1*E1, W2*E2, W3*E3);
    *(float4*)(rp+4)  = make_float4(W4*E4, W5*E5, W6*E6, W7*E7);
    *(float4*)(rp+8)  = make_float4(E8,    W7*E7, W6*E6, W5*E5);
    *(float4*)(rp+12) = make_float4(W4*E4, W3*E3, W2*E2, W1*E1);
  }
  __syncthreads();

  for (int i = tid; i < NW; i += 256) {
    int m = wbase + i;
    float val = 0.f;
    if (m >= 0 && m < LW) {
      int q = m + 8;
      int tq = q >> 2, r = q & 3;
      int base = (tq - tAlo) * FSTR + r;
      float acc = 0.f, env = 0.f;
#pragma unroll
      for (int j = 0; j < 4; ++j) {
        int t = tq - j;
        if ((unsigned)t < (unsigned)TFR) { acc += s_fab[base - 16*j]; env += W2C[r + 4*j]; }
      }
      val = acc * __builtin_amdgcn_rcpf(16.f * env);
    }
    s_wav[i] = val;
  }
  __syncthreads();

  for (int f = tid; f < NFB; f += 256) {
    float* rp = s_fab + f * FSTR;
    int t2 = tBlo + f;
    bool valid = ((unsigned)t2 < (unsigned)TFR);
    if (valid) {
      float xs[16];
      int g0 = 4*t2 - 8;
#pragma unroll
      for (int n = 0; n < 16; ++n) {
        int g = g0 + n;
        g = (g < 0) ? -g : g;
        g = (g < LW) ? g : (2*(LW-1) - g);
        xs[n] = s_wav[g - wbase];
      }
      float x1=xs[1]*W1, x2=xs[2]*W2, x3=xs[3]*W3, x4=xs[4]*W4, x5=xs[5]*W5,
            x6=xs[6]*W6, x7=xs[7]*W7, x8w=xs[8], x9=xs[9]*W7, x10=xs[10]*W6,
            x11=xs[11]*W5, x12=xs[12]*W4, x13=xs[13]*W3, x14=xs[14]*W2, x15=xs[15]*W1;
      float u1=x1+x15, v1=x1-x15, u2=x2+x14, v2=x2-x14, u3=x3+x13, v3=x3-x13,
            u4=x4+x12, v4=x4-x12, u5=x5+x11, v5=x5-x11, u6=x6+x10, v6=x6-x10,
            u7=x7+x9,  v7=x7-x9;
      float P1=u1+u7, M1=u1-u7, P2=u2+u6, M2=u2-u6, P3=u3+u5, M3=u3-u5;
      float D13 = P1-P3;
      float Sr0 = x8w + ((P1+P2)+(P3+u4));
      float Sr1 = fmaf(C1f,M1, fmaf(C2f,M2, C3f*M3)) - x8w;
      float Sr2 = fmaf(C2f,D13, x8w - u4);
      float Sr3 = fmaf(C3f,M1, fmaf(-C2f,M2, -C1f*M3)) - x8w;
      float Sr4 = (u4 - P2) + x8w;
      float Sr5 = fmaf(-C3f,M1, fmaf(-C2f,M2, C1f*M3)) - x8w;
      float Sr6 = fmaf(-C2f,D13, x8w - u4);
      float Sr7 = fmaf(-C1f,M1, fmaf(C2f,M2, -C3f*M3)) - x8w;
      float Sr8 = x8w + ((P2+u4)-(P1+P3));
      float Q1=v1+v7, N1=v1-v7, Q2=v2+v6, N2=v2-v6, Q3=v3+v5, N3=v3-v5;
      float NN = N1+N3;
      float Si1 = -(fmaf(C3f,Q1, fmaf(C2f,Q2, C1f*Q3)) + v4);
      float Si2 = -fmaf(C2f,NN, N2);
      float Si3 = -(fmaf(C1f,Q1, fmaf(C2f,Q2, -C3f*Q3)) - v4);
      float Si4 = N3 - N1;
      float Si5 = -(fmaf(C1f,Q1, fmaf(-C2f,Q2, -C3f*Q3)) + v4);
      float Si6 = fmaf(-C2f,NN, N2);
      float Si7 = -(fmaf(C3f,Q1, fmaf(-C2f,Q2, C1f*Q3)) - v4);

      const float* mcol = s_mag + (f + 3);
      float pr0,pr1,pr2,pr3,pr4,pr5,pr6,pr7,pr8;
      float pi1,pi2,pi3,pi4,pi5,pi6,pi7;
#define PHASE(PRk, PIk, kk, SR, SI) { \
      float mm = mcol[kk*MSTR]; \
      float r2 = fmaf(SR,SR, (SI)*(SI)); \
      float rin = (r2 > 0.f) ? __builtin_amdgcn_rsqf(r2) : 0.f; \
      float mr = mm * rin; \
      PRk = (r2 > 0.f) ? mr * (SR) : mm; \
      PIk = mr * (SI); }
      { float mm = mcol[0];
        pr0 = (Sr0 != 0.f) ? ((Sr0 > 0.f) ? mm : -mm) : mm; }
      PHASE(pr1, pi1, 1, Sr1, Si1)
      PHASE(pr2, pi2, 2, Sr2, Si2)
      PHASE(pr3, pi3, 3, Sr3, Si3)
      PHASE(pr4, pi4, 4, Sr4, Si4)
      PHASE(pr5, pi5, 5, Sr5, Si5)
      PHASE(pr6, pi6, 6, Sr6, Si6)
      PHASE(pr7, pi7, 7, Sr7, Si7)
      { float mm = mcol[8*MSTR];
        pr8 = (Sr8 != 0.f) ? ((Sr8 > 0.f) ? mm : -mm) : mm; }
#undef PHASE

      float ap1=pr1+pr7, bm1=pr1-pr7, ap2=pr2+pr6, bm2=pr2-pr6, ap3=pr3+pr5, bm3=pr3-pr5;
      float tp=pr0+pr8, tm=pr0-pr8, ed=ap1-ap3;
      float E1 = fmaf(2.f, fmaf(C1f,bm1, fmaf(C2f,bm2, C3f*bm3)), tm);
      float E2 = fmaf(2.f, fmaf(C2f,ed, -pr4), tp);
      float E3 = fmaf(2.f, fmaf(C3f,bm1, fmaf(-C2f,bm2, -C1f*bm3)), tm);
      float E4 = fmaf(2.f, pr4-ap2, tp);
      float E5 = fmaf(2.f, fmaf(-C3f,bm1, fmaf(-C2f,bm2, C1f*bm3)), tm);
      float E6 = fmaf(-2.f, fmaf(C2f,ed, pr4), tp);
      float E7 = fmaf(2.f, fmaf(-C1f,bm1, fmaf(C2f,bm2, -C3f*bm3)), tm);
      float E8 = fmaf(2.f, ((ap2+pr4)-(ap1+ap3)), tp);
      float q1=pi1+pi7, n1=pi1-pi7, q2=pi2+pi6, n2=pi2-pi6, q3=pi3+pi5, n3=pi3-pi5;
      float nn = n1+n3;
      float O1 = -2.f*(fmaf(C3f,q1, fmaf(C2f,q2, C1f*q3)) + pi4);
      float O2 = -2.f*fmaf(C2f,nn, n2);
      float O3 = -2.f*(fmaf(C1f,q1, fmaf(C2f,q2, -C3f*q3)) - pi4);
      float O4 = -2.f*(n1-n3);
      float O5 = -2.f*(fmaf(C1f,q1, fmaf(-C2f,q2, -C3f*q3)) + pi4);
      float O6 = -2.f*fmaf(C2f,nn, -n2);
      float O7 = -2.f*(fmaf(C3f,q1, fmaf(-C2f,q2, C1f*q3)) - pi4);

      *(float4*)(rp+0)  = make_float4(0.f,          W1*(E1+O1), W2*(E2+O2), W3*(E3+O3));
      *(float4*)(rp+4)  = make_float4(W4*(E4+O4),   W5*(E5+O5), W6*(E6+O6), W7*(E7+O7));
      *(float4*)(rp+8)  = make_float4(E8,           W7*(E7-O7), W6*(E6-O6), W5*(E5-O5));
      *(float4*)(rp+12) = make_float4(W4*(E4-O4),   W3*(E3-O3), W2*(E2-O2), W1*(E1-O1));
    } else {
      float4 z = make_float4(0.f,0.f,0.f,0.f);
      *(float4*)(rp+0)=z; *(float4*)(rp+4)=z; *(float4*)(rp+8)=z; *(float4*)(rp+12)=z;
    }
  }
  __syncthreads();

  float* outb = out + (size_t)b * LW;
  for (int i = tid; i < TILE; i += 256) {
    int l = l0 + i;
    if (l < LW) {
      int q = l + 8;
      int tq = q >> 2, r = q & 3;
      int base = (tq - tBlo) * FSTR + r;
      float acc = 0.f, env = 0.f;
#pragma unroll
      for (int j = 0; j < 4; ++j) {
        int t = tq - j;
        if ((unsigned)t < (unsigned)TFR) { acc += s_fab[base - 16*j]; env += W2C[r + 4*j]; }
      }
      outb[l] = acc * __builtin_amdgcn_rcpf(16.f * env);
    }
  }
}

extern "C" void kernel_launch(void* const* d_in, const int* in_sizes, int n_in,
                              void* d_out, int out_size, void* d_ws, size_t ws_size,
                              hipStream_t stream) {
  const float* mag = (const float*)d_in[0];   // (32, 9, 65536) f32
  float* out = (float*)d_out;                 // (32, 262140) f32
  // interior: out frames [256, 65280) -> 65024 frames, 55/wave, 4 waves/block
  int waves = (65024 + FRAMES_PER_WAVE - 1) / FRAMES_PER_WAVE;   // 1183
  int blocksx = (waves + 3) / 4;                                  // 296
  dim3 grid(blocksx, 32);
  istft_wave<<<grid, 256, 0, stream>>>(mag, out);
  dim3 egrid(2, 32);
  istft_edge<<<egrid, 256, 0, stream>>>(mag, out);
}

// Round 5
// 125.138 us; speedup vs baseline: 2.6136x; 1.0393x over previous
//
#include <hip/hip_runtime.h>

// Fully fused mag -> ISTFT -> STFT -> phase -> ISTFT.
// N_FFT=16, HOP=4, PAD=8. B=32, K=9 bins, T=65536 frames, LW=262140.
// Single kernel: interior blocks use wave-shuffle pipeline with 2 frames
// per lane (packed-f32 math, ds_bpermute halo exchange, zero LDS/barriers);
// 2 edge blocks per batch run the validated LDS pipeline for the first and
// last 1024 samples (reflect-pad + partial-env cases).

#define KB    9
#define TFR   65536
#define LW    262140

#define C1f 0.9238795325112867f
#define C2f 0.7071067811865476f
#define C3f 0.3826834323650898f

#define W1 0.03806023374435663f
#define W2 0.14644660940672627f
#define W3 0.30865828381745514f
#define W4 0.5f
#define W5 0.6913417161825449f
#define W6 0.8535533905932737f
#define W7 0.9619397662556434f

// interior coverage: out frames [256, 65280); 116 frames per wave
#define TMIN   256
#define TMAX   65280
#define FPW    116
#define NWAVES 561            // ceil(65024/116)
#define BXI    141            // ceil(561/4) interior blocks per batch

// edge tiles
#define TILE  1024
#define NW    1048
#define NCA   265
#define NFB   259
#define MSTR  268
#define FSTR  20

typedef float v2f __attribute__((ext_vector_type(2)));

static __device__ __forceinline__ v2f mk(float a, float b){ v2f r; r.x=a; r.y=b; return r; }
static __device__ __forceinline__ v2f sp(float c){ v2f r; r.x=c; r.y=c; return r; }
static __device__ __forceinline__ v2f vfma(v2f a, v2f b, v2f c){ return __builtin_elementwise_fma(a,b,c); }
static __device__ __forceinline__ v2f vfma(float a, v2f b, v2f c){ return __builtin_elementwise_fma(sp(a),b,c); }

static __device__ __forceinline__ void phase1(float m, float Sr, float Si,
                                              float& pr, float& pi){
  float r2 = fmaf(Sr,Sr, Si*Si);
  if (r2 > 0.f) {
    float rin = __builtin_amdgcn_rsqf(r2);
    float mr = m * rin;
    pr = mr * Sr; pi = mr * Si;
  } else { pr = m; pi = 0.f; }
}
static __device__ __forceinline__ void phasev(v2f m, v2f Sr, v2f Si, v2f& pr, v2f& pi){
  float prx, pix, pry, piy;
  phase1(m.x, Sr.x, Si.x, prx, pix);
  phase1(m.y, Sr.y, Si.y, pry, piy);
  pr = mk(prx, pry); pi = mk(pix, piy);
}

__device__ __constant__ float W2C[16] = {
  0.f, W1*W1, W2*W2, W3*W3, 0.25f, W5*W5, W6*W6, W7*W7,
  1.f, W7*W7, W6*W6, W5*W5, 0.25f, W3*W3, W2*W2, W1*W1 };

#define SH(x, di) __shfl((x), lane + (di), 64)

__global__ __launch_bounds__(256) void istft_all(
    const float* __restrict__ mag, float* __restrict__ out)
{
  // edge-path LDS (unused by interior blocks)
  __shared__ __align__(16) float s_mag[KB * MSTR];
  __shared__ __align__(16) float s_fab[NCA * FSTR];
  __shared__ __align__(16) float s_wav[NW];

  const int tid = threadIdx.x;
  const int bx  = blockIdx.x;
  const int b   = blockIdx.y;
  const float* magb = mag + (size_t)b * (size_t)(KB * TFR);
  float* outb = out + (size_t)b * LW;

  if (bx < BXI) {
    // ---------------- interior: 1 lane = 2 frames, shuffle halo ----------------
    const int lane = tid & 63;
    const int wv   = bx * 4 + (tid >> 6);
    if (wv >= NWAVES) return;
    const int T0 = TMIN + wv * FPW;
    const int ta = T0 - 6 + 2 * lane;       // even; lane's frame pair (ta, ta+1)

    // mag columns (ta, ta+1) for 9 bins: float2 loads, coalesced
    v2f R0 = *(const v2f*)(magb + 0*TFR + ta);
    v2f R1 = *(const v2f*)(magb + 1*TFR + ta);
    v2f R2 = *(const v2f*)(magb + 2*TFR + ta);
    v2f R3 = *(const v2f*)(magb + 3*TFR + ta);
    v2f R4 = *(const v2f*)(magb + 4*TFR + ta);
    v2f R5 = *(const v2f*)(magb + 5*TFR + ta);
    v2f R6 = *(const v2f*)(magb + 6*TFR + ta);
    v2f R7 = *(const v2f*)(magb + 7*TFR + ta);
    v2f R8 = *(const v2f*)(magb + 8*TFR + ta);

    // ---- stage A: irfft16 of real spectrum, windowed (symmetric frame) ----
    v2f f1,f2,f3,f4,f5,f6,f7,f8;
    {
      v2f p1=R1+R7, m1=R1-R7, p2=R2+R6, m2=R2-R6, p3=R3+R5, m3=R3-R5;
      v2f tp=R0+R8, tm=R0-R8, d13=p1-p3;
      v2f E1 = vfma(2.f, vfma(C1f,m1, vfma(C2f,m2, sp(C3f)*m3)), tm);
      v2f E2 = vfma(2.f, vfma(C2f,d13, -R4), tp);
      v2f E3 = vfma(2.f, vfma(C3f,m1, vfma(-C2f,m2, sp(-C1f)*m3)), tm);
      v2f E4 = vfma(2.f, R4-p2, tp);
      v2f E5 = vfma(2.f, vfma(-C3f,m1, vfma(-C2f,m2, sp(C1f)*m3)), tm);
      v2f E6 = vfma(-2.f, vfma(C2f,d13, R4), tp);
      v2f E7 = vfma(2.f, vfma(-C1f,m1, vfma(C2f,m2, sp(-C3f)*m3)), tm);
      v2f E8 = vfma(2.f, ((p2+R4)-(p1+p3)), tp);
      f1=sp(W1)*E1; f2=sp(W2)*E2; f3=sp(W3)*E3; f4=sp(W4)*E4;
      f5=sp(W5)*E5; f6=sp(W6)*E6; f7=sp(W7)*E7; f8=E8;
    }

    // ---- stage A2: OLA -> wav chunks wc[r] = wav[4t+r] pair ----
    v2f wc0, wc1, wc2, wc3;
    {
      float s4 = SH(f4.x,+1), s5 = SH(f5.x,+1), s6 = SH(f6.x,+1), s7 = SH(f7.x,+1);
      float a1x = SH(f1.x,+1), a1y = SH(f1.y,+1);
      float a2x = SH(f2.x,+1), a2y = SH(f2.y,+1);
      float a3x = SH(f3.x,+1), a3y = SH(f3.y,+1);
      float m1y = SH(f1.y,-1), m2y = SH(f2.y,-1), m3y = SH(f3.y,-1), m4y = SH(f4.y,-1);
      v2f f4p1 = mk(f4.y, s4), f5p1 = mk(f5.y, s5), f6p1 = mk(f6.y, s6), f7p1 = mk(f7.y, s7);
      v2f f1p2 = mk(a1x, a1y), f2p2 = mk(a2x, a2y), f3p2 = mk(a3x, a3y);
      v2f f1m1 = mk(m1y, f1.x), f2m1 = mk(m2y, f2.x), f3m1 = mk(m3y, f3.x), f4m1 = mk(m4y, f4.x);
      const v2f inv24 = sp(1.f/24.f);
      wc0 = (f4p1 + f8 + f4m1) * inv24;
      wc1 = (f1p2 + f5p1 + f7 + f3m1) * inv24;
      wc2 = (f2p2 + f6p1 + f6 + f2m1) * inv24;
      wc3 = (f3p2 + f7p1 + f5 + f1m1) * inv24;
    }

    // ---- stage B gather: xs[n] = wav[4t-8+n] pairs ----
    v2f x1,x2,x3,x4,x5,x6,x7,x8w,x9,x10,x11,x12,x13,x14,x15;
    {
      float aw0y = SH(wc0.y,-1);
      float aw1x = SH(wc1.x,-1), aw1y = SH(wc1.y,-1);
      float aw2x = SH(wc2.x,-1), aw2y = SH(wc2.y,-1);
      float aw3x = SH(wc3.x,-1), aw3y = SH(wc3.y,-1);
      float pw0x = SH(wc0.x,+1), pw1x = SH(wc1.x,+1), pw2x = SH(wc2.x,+1), pw3x = SH(wc3.x,+1);
      x1  = mk(aw1x, aw1y); x2  = mk(aw2x, aw2y); x3  = mk(aw3x, aw3y);
      x4  = mk(aw0y, wc0.x); x5 = mk(aw1y, wc1.x); x6 = mk(aw2y, wc2.x); x7 = mk(aw3y, wc3.x);
      x8w = wc0; x9 = wc1; x10 = wc2; x11 = wc3;
      x12 = mk(wc0.y, pw0x); x13 = mk(wc1.y, pw1x); x14 = mk(wc2.y, pw2x); x15 = mk(wc3.y, pw3x);
    }
    // window (w0=0 kills tap 0; w8=1)
    x1=sp(W1)*x1; x2=sp(W2)*x2; x3=sp(W3)*x3; x4=sp(W4)*x4; x5=sp(W5)*x5;
    x6=sp(W6)*x6; x7=sp(W7)*x7; x9=sp(W7)*x9; x10=sp(W6)*x10; x11=sp(W5)*x11;
    x12=sp(W4)*x12; x13=sp(W3)*x13; x14=sp(W2)*x14; x15=sp(W1)*x15;

    v2f fc1,fc2,fc3,fc4,fc5,fc6,fc7,fc8,fc9,fc10,fc11,fc12,fc13,fc14,fc15;
    {
      v2f u1=x1+x15, vv1=x1-x15, u2=x2+x14, vv2=x2-x14, u3=x3+x13, vv3=x3-x13,
          u4=x4+x12, vv4=x4-x12, u5=x5+x11, vv5=x5-x11, u6=x6+x10, vv6=x6-x10,
          u7=x7+x9,  vv7=x7-x9;
      v2f P1=u1+u7, M1=u1-u7, P2=u2+u6, M2=u2-u6, P3=u3+u5, M3=u3-u5;
      v2f D13 = P1-P3;
      v2f Sr0 = x8w + ((P1+P2)+(P3+u4));
      v2f Sr1 = vfma(C1f,M1, vfma(C2f,M2, sp(C3f)*M3)) - x8w;
      v2f Sr2 = vfma(C2f,D13, x8w - u4);
      v2f Sr3 = vfma(C3f,M1, vfma(-C2f,M2, sp(-C1f)*M3)) - x8w;
      v2f Sr4 = (u4 - P2) + x8w;
      v2f Sr5 = vfma(-C3f,M1, vfma(-C2f,M2, sp(C1f)*M3)) - x8w;
      v2f Sr6 = vfma(-C2f,D13, x8w - u4);
      v2f Sr7 = vfma(-C1f,M1, vfma(C2f,M2, sp(-C3f)*M3)) - x8w;
      v2f Sr8 = x8w + ((P2+u4)-(P1+P3));
      v2f Q1=vv1+vv7, N1=vv1-vv7, Q2=vv2+vv6, N2=vv2-vv6, Q3=vv3+vv5, N3=vv3-vv5;
      v2f NN = N1+N3;
      v2f Si1 = -(vfma(C3f,Q1, vfma(C2f,Q2, sp(C1f)*Q3)) + vv4);
      v2f Si2 = -vfma(C2f,NN, N2);
      v2f Si3 = -(vfma(C1f,Q1, vfma(C2f,Q2, sp(-C3f)*Q3)) - vv4);
      v2f Si4 = N3 - N1;
      v2f Si5 = -(vfma(C1f,Q1, vfma(-C2f,Q2, sp(-C3f)*Q3)) + vv4);
      v2f Si6 = vfma(-C2f,NN, N2);
      v2f Si7 = -(vfma(C3f,Q1, vfma(-C2f,Q2, sp(C1f)*Q3)) - vv4);

      // phase recombine
      v2f pr0,pr1,pr2,pr3,pr4,pr5,pr6,pr7,pr8;
      v2f pi1,pi2,pi3,pi4,pi5,pi6,pi7;
      pr0 = mk((Sr0.x >= 0.f) ? R0.x : -R0.x,
               (Sr0.y >= 0.f) ? R0.y : -R0.y);
      phasev(R1, Sr1, Si1, pr1, pi1);
      phasev(R2, Sr2, Si2, pr2, pi2);
      phasev(R3, Sr3, Si3, pr3, pi3);
      phasev(R4, Sr4, Si4, pr4, pi4);
      phasev(R5, Sr5, Si5, pr5, pi5);
      phasev(R6, Sr6, Si6, pr6, pi6);
      phasev(R7, Sr7, Si7, pr7, pi7);
      pr8 = mk((Sr8.x >= 0.f) ? R8.x : -R8.x,
               (Sr8.y >= 0.f) ? R8.y : -R8.y);

      // irfft16 of (pr + i*pi), windowed
      v2f ap1=pr1+pr7, bm1=pr1-pr7, ap2=pr2+pr6, bm2=pr2-pr6, ap3=pr3+pr5, bm3=pr3-pr5;
      v2f tp=pr0+pr8, tm=pr0-pr8, ed=ap1-ap3;
      v2f E1 = vfma(2.f, vfma(C1f,bm1, vfma(C2f,bm2, sp(C3f)*bm3)), tm);
      v2f E2 = vfma(2.f, vfma(C2f,ed, -pr4), tp);
      v2f E3 = vfma(2.f, vfma(C3f,bm1, vfma(-C2f,bm2, sp(-C1f)*bm3)), tm);
      v2f E4 = vfma(2.f, pr4-ap2, tp);
      v2f E5 = vfma(2.f, vfma(-C3f,bm1, vfma(-C2f,bm2, sp(C1f)*bm3)), tm);
      v2f E6 = vfma(-2.f, vfma(C2f,ed, pr4), tp);
      v2f E7 = vfma(2.f, vfma(-C1f,bm1, vfma(C2f,bm2, sp(-C3f)*bm3)), tm);
      v2f E8 = vfma(2.f, ((ap2+pr4)-(ap1+ap3)), tp);
      v2f q1=pi1+pi7, n1=pi1-pi7, q2=pi2+pi6, n2=pi2-pi6, q3=pi3+pi5, n3=pi3-pi5;
      v2f nn = n1+n3;
      v2f O1 = sp(-2.f)*(vfma(C3f,q1, vfma(C2f,q2, sp(C1f)*q3)) + pi4);
      v2f O2 = sp(-2.f)*vfma(C2f,nn, n2);
      v2f O3 = sp(-2.f)*(vfma(C1f,q1, vfma(C2f,q2, sp(-C3f)*q3)) - pi4);
      v2f O4 = sp(-2.f)*(n1-n3);
      v2f O5 = sp(-2.f)*(vfma(C1f,q1, vfma(-C2f,q2, sp(-C3f)*q3)) + pi4);
      v2f O6 = sp(-2.f)*vfma(C2f,nn, -n2);
      v2f O7 = sp(-2.f)*(vfma(C3f,q1, vfma(-C2f,q2, sp(C1f)*q3)) - pi4);

      fc1 = sp(W1)*(E1+O1); fc2 = sp(W2)*(E2+O2); fc3 = sp(W3)*(E3+O3); fc4 = sp(W4)*(E4+O4);
      fc5 = sp(W5)*(E5+O5); fc6 = sp(W6)*(E6+O6); fc7 = sp(W7)*(E7+O7); fc8 = E8;
      fc9  = sp(W7)*(E7-O7); fc10 = sp(W6)*(E6-O6); fc11 = sp(W5)*(E5-O5); fc12 = sp(W4)*(E4-O4);
      fc13 = sp(W3)*(E3-O3); fc14 = sp(W2)*(E2-O2); fc15 = sp(W1)*(E1-O1);
    }

    // ---- stage C: final OLA -> out[4ta .. 4ta+7] ----
    {
      float c1x = SH(fc1.x,+1), c1y = SH(fc1.y,+1);
      float c2x = SH(fc2.x,+1), c2y = SH(fc2.y,+1);
      float c3x = SH(fc3.x,+1), c3y = SH(fc3.y,+1);
      float c4x = SH(fc4.x,+1), c5x = SH(fc5.x,+1), c6x = SH(fc6.x,+1), c7x = SH(fc7.x,+1);
      float d12 = SH(fc12.y,-1), d13s = SH(fc13.y,-1), d14 = SH(fc14.y,-1), d15 = SH(fc15.y,-1);
      v2f g1 = mk(c1x, c1y), g2 = mk(c2x, c2y), g3 = mk(c3x, c3y);
      v2f h4 = mk(fc4.y, c4x), h5 = mk(fc5.y, c5x), h6 = mk(fc6.y, c6x), h7 = mk(fc7.y, c7x);
      v2f q12 = mk(d12, fc12.x), q13 = mk(d13s, fc13.x), q14 = mk(d14, fc14.x), q15 = mk(d15, fc15.x);
      const v2f inv24 = sp(1.f/24.f);
      v2f o0 = (h4 + fc8  + q12) * inv24;
      v2f o1 = (g1 + h5 + fc9  + q13) * inv24;
      v2f o2 = (g2 + h6 + fc10 + q14) * inv24;
      v2f o3 = (g3 + h7 + fc11 + q15) * inv24;
      if (lane >= 3 && lane <= 60 && ta < TMAX) {
        float4 s0; s0.x=o0.x; s0.y=o1.x; s0.z=o2.x; s0.w=o3.x;
        float4 s1; s1.x=o0.y; s1.y=o1.y; s1.z=o2.y; s1.w=o3.y;
        *(float4*)(outb + 4*(size_t)ta)     = s0;
        *(float4*)(outb + 4*(size_t)ta + 4) = s1;
      }
    }
    return;
  }

  // ---------------- edge blocks: validated LDS pipeline ----------------
  const int l0  = (bx == BXI) ? 0 : 261120;
  const int t4  = l0 >> 2;
  const int tAlo = t4 - 4;
  const int tBlo = t4 - 1;
  const int wbase = l0 - 12;

#pragma unroll
  for (int k = 0; k < KB; ++k) {
    const float* mrow = magb + (size_t)k * TFR + tAlo;
    for (int c = tid; c < NCA; c += 256) {
      int t = tAlo + c;
      s_mag[k * MSTR + c] = ((unsigned)t < (unsigned)TFR) ? mrow[c] : 0.f;
    }
  }
  __syncthreads();

  for (int f = tid; f < NCA; f += 256) {
    float R0 = s_mag[0*MSTR+f], R1 = s_mag[1*MSTR+f], R2 = s_mag[2*MSTR+f],
          R3 = s_mag[3*MSTR+f], R4 = s_mag[4*MSTR+f], R5 = s_mag[5*MSTR+f],
          R6 = s_mag[6*MSTR+f], R7 = s_mag[7*MSTR+f], R8 = s_mag[8*MSTR+f];
    float p1=R1+R7, m1=R1-R7, p2=R2+R6, m2=R2-R6, p3=R3+R5, m3=R3-R5;
    float tp=R0+R8, tm=R0-R8, d13=p1-p3;
    float E1 = fmaf(2.f, fmaf(C1f,m1, fmaf(C2f,m2, C3f*m3)), tm);
    float E2 = fmaf(2.f, fmaf(C2f,d13, -R4), tp);
    float E3 = fmaf(2.f, fmaf(C3f,m1, fmaf(-C2f,m2, -C1f*m3)), tm);
    float E4 = fmaf(2.f, R4-p2, tp);
    float E5 = fmaf(2.f, fmaf(-C3f,m1, fmaf(-C2f,m2, C1f*m3)), tm);
    float E6 = fmaf(-2.f, fmaf(C2f,d13, R4), tp);
    float E7 = fmaf(2.f, fmaf(-C1f,m1, fmaf(C2f,m2, -C3f*m3)), tm);
    float E8 = fmaf(2.f, ((p2+R4)-(p1+p3)), tp);
    float* rp = s_fab + f * FSTR;
    *(float4*)(rp+0)  = make_float4(0.f,   W1*E1, W2*E2, W3*E3);
    *(float4*)(rp+4)  = make_float4(W4*E4, W5*E5, W6*E6, W7*E7);
    *(float4*)(rp+8)  = make_float4(E8,    W7*E7, W6*E6, W5*E5);
    *(float4*)(rp+12) = make_float4(W4*E4, W3*E3, W2*E2, W1*E1);
  }
  __syncthreads();

  for (int i = tid; i < NW; i += 256) {
    int m = wbase + i;
    float val = 0.f;
    if (m >= 0 && m < LW) {
      int q = m + 8;
      int tq = q >> 2, r = q & 3;
      int base = (tq - tAlo) * FSTR + r;
      float acc = 0.f, env = 0.f;
#pragma unroll
      for (int j = 0; j < 4; ++j) {
        int t = tq - j;
        if ((unsigned)t < (unsigned)TFR) { acc += s_fab[base - 16*j]; env += W2C[r + 4*j]; }
      }
      val = acc * __builtin_amdgcn_rcpf(16.f * env);
    }
    s_wav[i] = val;
  }
  __syncthreads();

  for (int f = tid; f < NFB; f += 256) {
    float* rp = s_fab + f * FSTR;
    int t2 = tBlo + f;
    bool valid = ((unsigned)t2 < (unsigned)TFR);
    if (valid) {
      float xs[16];
      int g0 = 4*t2 - 8;
#pragma unroll
      for (int n = 0; n < 16; ++n) {
        int g = g0 + n;
        g = (g < 0) ? -g : g;
        g = (g < LW) ? g : (2*(LW-1) - g);
        xs[n] = s_wav[g - wbase];
      }
      float x1=xs[1]*W1, x2=xs[2]*W2, x3=xs[3]*W3, x4=xs[4]*W4, x5=xs[5]*W5,
            x6=xs[6]*W6, x7=xs[7]*W7, x8w=xs[8], x9=xs[9]*W7, x10=xs[10]*W6,
            x11=xs[11]*W5, x12=xs[12]*W4, x13=xs[13]*W3, x14=xs[14]*W2, x15=xs[15]*W1;
      float u1=x1+x15, v1=x1-x15, u2=x2+x14, v2=x2-x14, u3=x3+x13, v3=x3-x13,
            u4=x4+x12, v4=x4-x12, u5=x5+x11, v5=x5-x11, u6=x6+x10, v6=x6-x10,
            u7=x7+x9,  v7=x7-x9;
      float P1=u1+u7, M1=u1-u7, P2=u2+u6, M2=u2-u6, P3=u3+u5, M3=u3-u5;
      float D13 = P1-P3;
      float Sr0 = x8w + ((P1+P2)+(P3+u4));
      float Sr1 = fmaf(C1f,M1, fmaf(C2f,M2, C3f*M3)) - x8w;
      float Sr2 = fmaf(C2f,D13, x8w - u4);
      float Sr3 = fmaf(C3f,M1, fmaf(-C2f,M2, -C1f*M3)) - x8w;
      float Sr4 = (u4 - P2) + x8w;
      float Sr5 = fmaf(-C3f,M1, fmaf(-C2f,M2, C1f*M3)) - x8w;
      float Sr6 = fmaf(-C2f,D13, x8w - u4);
      float Sr7 = fmaf(-C1f,M1, fmaf(C2f,M2, -C3f*M3)) - x8w;
      float Sr8 = x8w + ((P2+u4)-(P1+P3));
      float Q1=v1+v7, N1=v1-v7, Q2=v2+v6, N2=v2-v6, Q3=v3+v5, N3=v3-v5;
      float NN = N1+N3;
      float Si1 = -(fmaf(C3f,Q1, fmaf(C2f,Q2, C1f*Q3)) + v4);
      float Si2 = -fmaf(C2f,NN, N2);
      float Si3 = -(fmaf(C1f,Q1, fmaf(C2f,Q2, -C3f*Q3)) - v4);
      float Si4 = N3 - N1;
      float Si5 = -(fmaf(C1f,Q1, fmaf(-C2f,Q2, -C3f*Q3)) + v4);
      float Si6 = fmaf(-C2f,NN, N2);
      float Si7 = -(fmaf(C3f,Q1, fmaf(-C2f,Q2, C1f*Q3)) - v4);

      const float* mcol = s_mag + (f + 3);
      float pr0,pr1,pr2,pr3,pr4,pr5,pr6,pr7,pr8;
      float pi1,pi2,pi3,pi4,pi5,pi6,pi7;
      { float mm = mcol[0];
        pr0 = (Sr0 >= 0.f) ? mm : -mm; }
      phase1(mcol[1*MSTR], Sr1, Si1, pr1, pi1);
      phase1(mcol[2*MSTR], Sr2, Si2, pr2, pi2);
      phase1(mcol[3*MSTR], Sr3, Si3, pr3, pi3);
      phase1(mcol[4*MSTR], Sr4, Si4, pr4, pi4);
      phase1(mcol[5*MSTR], Sr5, Si5, pr5, pi5);
      phase1(mcol[6*MSTR], Sr6, Si6, pr6, pi6);
      phase1(mcol[7*MSTR], Sr7, Si7, pr7, pi7);
      { float mm = mcol[8*MSTR];
        pr8 = (Sr8 >= 0.f) ? mm : -mm; }

      float ap1=pr1+pr7, bm1=pr1-pr7, ap2=pr2+pr6, bm2=pr2-pr6, ap3=pr3+pr5, bm3=pr3-pr5;
      float tp=pr0+pr8, tm=pr0-pr8, ed=ap1-ap3;
      float E1 = fmaf(2.f, fmaf(C1f,bm1, fmaf(C2f,bm2, C3f*bm3)), tm);
      float E2 = fmaf(2.f, fmaf(C2f,ed, -pr4), tp);
      float E3 = fmaf(2.f, fmaf(C3f,bm1, fmaf(-C2f,bm2, -C1f*bm3)), tm);
      float E4 = fmaf(2.f, pr4-ap2, tp);
      float E5 = fmaf(2.f, fmaf(-C3f,bm1, fmaf(-C2f,bm2, C1f*bm3)), tm);
      float E6 = fmaf(-2.f, fmaf(C2f,ed, pr4), tp);
      float E7 = fmaf(2.f, fmaf(-C1f,bm1, fmaf(C2f,bm2, -C3f*bm3)), tm);
      float E8 = fmaf(2.f, ((ap2+pr4)-(ap1+ap3)), tp);
      float q1=pi1+pi7, n1=pi1-pi7, q2=pi2+pi6, n2=pi2-pi6, q3=pi3+pi5, n3=pi3-pi5;
      float nn = n1+n3;
      float O1 = -2.f*(fmaf(C3f,q1, fmaf(C2f,q2, C1f*q3)) + pi4);
      float O2 = -2.f*fmaf(C2f,nn, n2);
      float O3 = -2.f*(fmaf(C1f,q1, fmaf(C2f,q2, -C3f*q3)) - pi4);
      float O4 = -2.f*(n1-n3);
      float O5 = -2.f*(fmaf(C1f,q1, fmaf(-C2f,q2, -C3f*q3)) + pi4);
      float O6 = -2.f*fmaf(C2f,nn, -n2);
      float O7 = -2.f*(fmaf(C3f,q1, fmaf(-C2f,q2, C1f*q3)) - pi4);

      *(float4*)(rp+0)  = make_float4(0.f,          W1*(E1+O1), W2*(E2+O2), W3*(E3+O3));
      *(float4*)(rp+4)  = make_float4(W4*(E4+O4),   W5*(E5+O5), W6*(E6+O6), W7*(E7+O7));
      *(float4*)(rp+8)  = make_float4(E8,           W7*(E7-O7), W6*(E6-O6), W5*(E5-O5));
      *(float4*)(rp+12) = make_float4(W4*(E4-O4),   W3*(E3-O3), W2*(E2-O2), W1*(E1-O1));
    } else {
      float4 z = make_float4(0.f,0.f,0.f,0.f);
      *(float4*)(rp+0)=z; *(float4*)(rp+4)=z; *(float4*)(rp+8)=z; *(float4*)(rp+12)=z;
    }
  }
  __syncthreads();

  for (int i = tid; i < TILE; i += 256) {
    int l = l0 + i;
    if (l < LW) {
      int q = l + 8;
      int tq = q >> 2, r = q & 3;
      int base = (tq - tBlo) * FSTR + r;
      float acc = 0.f, env = 0.f;
#pragma unroll
      for (int j = 0; j < 4; ++j) {
        int t = tq - j;
        if ((unsigned)t < (unsigned)TFR) { acc += s_fab[base - 16*j]; env += W2C[r + 4*j]; }
      }
      outb[l] = acc * __builtin_amdgcn_rcpf(16.f * env);
    }
  }
}

extern "C" void kernel_launch(void* const* d_in, const int* in_sizes, int n_in,
                              void* d_out, int out_size, void* d_ws, size_t ws_size,
                              hipStream_t stream) {
  const float* mag = (const float*)d_in[0];   // (32, 9, 65536) f32
  float* out = (float*)d_out;                 // (32, 262140) f32
  dim3 grid(BXI + 2, 32);                     // 141 interior + 2 edge blocks/batch
  istft_all<<<grid, 256, 0, stream>>>(mag, out);
}